// Round 5
// baseline (1257.294 us; speedup 1.0000x reference)
//
#include <hip/hip_runtime.h>
#include <hip/hip_bf16.h>
#include <math.h>

// TokenMoE: x[4,2048,1024] fp32, 8 experts, top-2, D_FF=4096, exact-erf GELU.
// Plan: gate (fp32) -> per-expert lists -> bf16 grouped GEMMs (MFMA) -> weighted scatter.
// ws needed ~272 MB.

#define D_MODEL 1024
#define N_EXPERTS 8
#define D_FF 4096
#define N_TOKENS 8192

typedef __attribute__((ext_vector_type(8))) short bf16x8;
typedef __attribute__((ext_vector_type(4))) float f32x4;
typedef __attribute__((ext_vector_type(8))) unsigned short ushort8;

__device__ inline unsigned short f2bf(float f) {
    unsigned int u = __float_as_uint(f);
    unsigned int r = (u + 0x7FFFu + ((u >> 16) & 1u)) >> 16;   // RNE
    return (unsigned short)r;
}

__device__ inline void gload_lds16(const void* g, void* l) {
    __builtin_amdgcn_global_load_lds(
        (const __attribute__((address_space(1))) unsigned int*)g,
        (__attribute__((address_space(3))) unsigned int*)l, 16, 0, 0);
}

// ---------------- fp32 -> bf16 conversion, 3 segments fused (8 elems/thread) -------------
__device__ inline void cvt8(const float* __restrict__ src, unsigned short* __restrict__ dst,
                            int i) {
    const float4* s = reinterpret_cast<const float4*>(src) + (size_t)i * 2;
    float4 a = s[0], b = s[1];
    ushort8 r;
    r[0] = f2bf(a.x); r[1] = f2bf(a.y); r[2] = f2bf(a.z); r[3] = f2bf(a.w);
    r[4] = f2bf(b.x); r[5] = f2bf(b.y); r[6] = f2bf(b.z); r[7] = f2bf(b.w);
    *reinterpret_cast<ushort8*>(dst + (size_t)i * 8) = r;
}

__global__ __launch_bounds__(256) void cvt_all(const float* __restrict__ s0, unsigned short* __restrict__ d0, int n0,
                                               const float* __restrict__ s1, unsigned short* __restrict__ d1, int n1,
                                               const float* __restrict__ s2, unsigned short* __restrict__ d2, int n2) {
    int i = blockIdx.x * blockDim.x + threadIdx.x;
    int stride = gridDim.x * blockDim.x;
    int total = n0 + n1 + n2;
    for (; i < total; i += stride) {
        if (i < n0)            cvt8(s0, d0, i);
        else if (i < n0 + n1)  cvt8(s1, d1, i - n0);
        else                   cvt8(s2, d2, i - n0 - n1);
    }
}

// ---------------- gating: logits, softmax, top-2, fill expert lists ----------------
// one wave per token; 4 tokens per 256-thread block
__global__ __launch_bounds__(256) void gate_kernel(const float* __restrict__ x,
                                                   const float* __restrict__ gw,
                                                   int* __restrict__ counts,
                                                   int* __restrict__ list,
                                                   float* __restrict__ pairw) {
    int wave = threadIdx.x >> 6;
    int lane = threadIdx.x & 63;
    int t = blockIdx.x * 4 + wave;
    if (t >= N_TOKENS) return;

    const float4* xr = reinterpret_cast<const float4*>(x + (size_t)t * D_MODEL);
    float4 xv[4];
#pragma unroll
    for (int i = 0; i < 4; i++) xv[i] = xr[lane + 64 * i];

    float acc[N_EXPERTS];
#pragma unroll
    for (int e = 0; e < N_EXPERTS; e++) {
        const float4* gr = reinterpret_cast<const float4*>(gw + (size_t)e * D_MODEL);
        float s = 0.f;
#pragma unroll
        for (int i = 0; i < 4; i++) {
            float4 g = gr[lane + 64 * i];
            s += xv[i].x * g.x + xv[i].y * g.y + xv[i].z * g.z + xv[i].w * g.w;
        }
        acc[e] = s;
    }
#pragma unroll
    for (int e = 0; e < N_EXPERTS; e++) {
        float s = acc[e];
#pragma unroll
        for (int off = 32; off; off >>= 1) s += __shfl_xor(s, off, 64);
        acc[e] = s;
    }
    if (lane == 0) {
        float m = acc[0];
#pragma unroll
        for (int e = 1; e < N_EXPERTS; e++) m = fmaxf(m, acc[e]);
        float p[N_EXPERTS], sum = 0.f;
#pragma unroll
        for (int e = 0; e < N_EXPERTS; e++) { p[e] = expf(acc[e] - m); sum += p[e]; }
        float inv = 1.f / sum;
#pragma unroll
        for (int e = 0; e < N_EXPERTS; e++) p[e] *= inv;
        int i1 = 0;
#pragma unroll
        for (int e = 1; e < N_EXPERTS; e++) if (p[e] > p[i1]) i1 = e;
        int i2 = (i1 == 0) ? 1 : 0;
#pragma unroll
        for (int e = 0; e < N_EXPERTS; e++) {
            if (e == i1) continue;
            if (p[e] > p[i2]) i2 = e;
        }
        int pos1 = atomicAdd(&counts[i1], 1);
        list[i1 * N_TOKENS + pos1] = t * 2 + 0;
        pairw[i1 * N_TOKENS + pos1] = p[i1];
        int pos2 = atomicAdd(&counts[i2], 1);
        list[i2 * N_TOKENS + pos2] = t * 2 + 1;
        pairw[i2 * N_TOKENS + pos2] = p[i2];
    }
}

// ---------------- grouped GEMM (m97-style: 128x128 tile, BK=64, 4 waves, 16x16x32 MFMA) ----
// LAYER==1: h[pid] = gelu(x[t] @ w1[e]^T + b1[e]), pid = list entry = t*2+k
// LAYER==2: out[t] += pairw * (h[pid] @ w2[e]^T + b2[e])
template <int LAYER>
__global__ __launch_bounds__(256) void moe_gemm(const unsigned short* __restrict__ A_src,
                                                const unsigned short* __restrict__ B_src,
                                                const float* __restrict__ bias,
                                                const int* __restrict__ counts,
                                                const int* __restrict__ list,
                                                const float* __restrict__ pairw,
                                                unsigned short* __restrict__ h_out,
                                                float* __restrict__ y_out) {
    constexpr int KD = (LAYER == 1) ? D_MODEL : D_FF;   // reduction dim
    constexpr int NO = (LAYER == 1) ? D_FF : D_MODEL;   // output cols
    const int e = blockIdx.z;
    const int cnt = counts[e];
    const int m0 = blockIdx.y * 128;
    if (m0 >= cnt) return;
    const int n0 = blockIdx.x * 128;

    __shared__ __align__(16) unsigned short As[128 * 64];
    __shared__ __align__(16) unsigned short Bs[128 * 64];

    const int tid = threadIdx.x;
    const int wave = tid >> 6, lane = tid & 63;
    const int lr = lane >> 3;        // row within 8-row staging chunk
    const int lc = (lane & 7) * 8;   // bf16-element offset within row (16B/lane)

    const unsigned short* aptr[4];
    const unsigned short* bptr[4];
#pragma unroll
    for (int i = 0; i < 4; i++) {
        int c = wave * 4 + i;
        int ra = c * 8 + lr;                       // tile row 0..127
        int pos = m0 + ra;
        int cpos = pos < cnt ? pos : (cnt - 1);
        int entry = list[e * N_TOKENS + cpos];
        long arow = (LAYER == 1) ? (long)(entry >> 1) : (long)entry;
        aptr[i] = A_src + arow * KD + lc;
        long brow = (long)e * NO + n0 + ra;
        bptr[i] = B_src + brow * KD + lc;
    }

    f32x4 acc[4][4];
#pragma unroll
    for (int m = 0; m < 4; m++)
#pragma unroll
        for (int n = 0; n < 4; n++) acc[m][n] = f32x4{0.f, 0.f, 0.f, 0.f};

    const int wr = (wave >> 1) * 64, wc = (wave & 1) * 64;
    const int fr = lane & 15;        // fragment row (A) / out-col (B)
    const int fk = (lane >> 4) * 8;  // fragment k offset

    for (int k0 = 0; k0 < KD; k0 += 64) {
        __syncthreads();  // previous tile's readers done
#pragma unroll
        for (int i = 0; i < 4; i++) {
            int c = wave * 4 + i;
            gload_lds16(aptr[i] + k0, &As[c * 8 * 64]);
            gload_lds16(bptr[i] + k0, &Bs[c * 8 * 64]);
        }
        __syncthreads();  // compiler drains vmcnt(0) before s_barrier
#pragma unroll
        for (int ks = 0; ks < 64; ks += 32) {
            bf16x8 af[4], bfr[4];
#pragma unroll
            for (int m = 0; m < 4; m++)
                af[m] = *reinterpret_cast<const bf16x8*>(&As[(wr + m * 16 + fr) * 64 + ks + fk]);
#pragma unroll
            for (int n = 0; n < 4; n++)
                bfr[n] = *reinterpret_cast<const bf16x8*>(&Bs[(wc + n * 16 + fr) * 64 + ks + fk]);
#pragma unroll
            for (int m = 0; m < 4; m++)
#pragma unroll
                for (int n = 0; n < 4; n++)
                    acc[m][n] = __builtin_amdgcn_mfma_f32_16x16x32_bf16(af[m], bfr[n], acc[m][n], 0, 0, 0);
        }
    }

    // epilogue: C/D layout col=lane&15, row=(lane>>4)*4+j  [verified m89/m91]
#pragma unroll
    for (int m = 0; m < 4; m++) {
#pragma unroll
        for (int j = 0; j < 4; j++) {
            int row = wr + m * 16 + ((lane >> 4) << 2) + j;
            int pos = m0 + row;
            if (pos >= cnt) continue;
            int entry = list[e * N_TOKENS + pos];
            if (LAYER == 1) {
                unsigned short* hrow = h_out + (long)entry * D_FF + n0;
#pragma unroll
                for (int n = 0; n < 4; n++) {
                    int col = wc + n * 16 + (lane & 15);
                    float v = acc[m][n][j] + bias[e * NO + n0 + col];
                    v = 0.5f * v * (1.f + erff(v * 0.70710678118654752440f));  // exact GELU
                    hrow[col] = f2bf(v);
                }
            } else {
                float w = pairw[e * N_TOKENS + pos];
                float* yrow = y_out + (long)(entry >> 1) * D_MODEL + n0;
#pragma unroll
                for (int n = 0; n < 4; n++) {
                    int col = wc + n * 16 + (lane & 15);
                    float v = (acc[m][n][j] + bias[e * NO + n0 + col]) * w;
                    atomicAdd(&yrow[col], v);
                }
            }
        }
    }
}

extern "C" void kernel_launch(void* const* d_in, const int* in_sizes, int n_in,
                              void* d_out, int out_size, void* d_ws, size_t ws_size,
                              hipStream_t stream) {
    const float* x  = (const float*)d_in[0];
    const float* gw = (const float*)d_in[1];
    const float* w1 = (const float*)d_in[2];
    const float* b1 = (const float*)d_in[3];
    const float* w2 = (const float*)d_in[4];
    const float* b2 = (const float*)d_in[5];
    float* out = (float*)d_out;

    char* ws = (char*)d_ws;
    size_t off = 0;
    auto alloc = [&](size_t bytes) {
        void* p = ws + off;
        off += (bytes + 255) & ~(size_t)255;
        return p;
    };
    unsigned short* x_bf  = (unsigned short*)alloc(sizeof(unsigned short) * N_TOKENS * D_MODEL);
    unsigned short* w1_bf = (unsigned short*)alloc(sizeof(unsigned short) * N_EXPERTS * D_FF * D_MODEL);
    unsigned short* w2_bf = (unsigned short*)alloc(sizeof(unsigned short) * N_EXPERTS * D_MODEL * D_FF);
    unsigned short* h_bf  = (unsigned short*)alloc(sizeof(unsigned short) * (size_t)N_TOKENS * 2 * D_FF);
    int*   list  = (int*)alloc(sizeof(int) * N_EXPERTS * N_TOKENS);
    float* pairw = (float*)alloc(sizeof(float) * N_EXPERTS * N_TOKENS);
    int*   counts = (int*)alloc(sizeof(int) * N_EXPERTS);

    hipMemsetAsync(counts, 0, sizeof(int) * N_EXPERTS, stream);
    hipMemsetAsync(out, 0, sizeof(float) * (size_t)N_TOKENS * D_MODEL, stream);

    cvt_all<<<2048, 256, 0, stream>>>(
        x,  x_bf,  N_TOKENS * D_MODEL / 8,
        w1, w1_bf, N_EXPERTS * D_FF * D_MODEL / 8,
        w2, w2_bf, N_EXPERTS * D_MODEL * D_FF / 8);

    gate_kernel<<<N_TOKENS / 4, 256, 0, stream>>>(x, gw, counts, list, pairw);

    moe_gemm<1><<<dim3(D_FF / 128, N_TOKENS / 128, N_EXPERTS), 256, 0, stream>>>(
        x_bf, w1_bf, b1, counts, list, pairw, h_bf, nullptr);
    moe_gemm<2><<<dim3(D_MODEL / 128, N_TOKENS / 128, N_EXPERTS), 256, 0, stream>>>(
        h_bf, w2_bf, b2, counts, list, pairw, nullptr, out);
}